// Round 4
// baseline (69503.583 us; speedup 1.0000x reference)
//
#include <hip/hip_runtime.h>

#define T_    300
#define B_    16
#define S_    160
#define NMEL_ 80
#define PRE_  256
#define ENC_  512
#define ATT_  128
#define DIM_  1024

#define XST1  1288     // P1 tile stride (mel 256 + h0 1024 + pad 8)
#define XST2  520      // P2 align tile stride
#define XST3  1032     // P3 h0 tile stride
#define WOFF  16704    // attn blocks: weff copy lives at xt[WOFF..WOFF+4096)
#define XTOT  20800    // dynamic LDS floats (83.2 KB)
#define BARWORDS 17408

typedef unsigned int u32;

__device__ __forceinline__ float fexp2f(float x) { return __builtin_amdgcn_exp2f(x); }
__device__ __forceinline__ float fsigf(float x)  { return 1.0f / (1.0f + fexp2f(-1.442695041f * x)); }
__device__ __forceinline__ float ftanhf(float x) {
  float xc = fminf(fmaxf(x, -15.0f), 15.0f);
  float e = fexp2f(2.885390082f * xc);
  return (e - 1.0f) / (e + 1.0f);
}

// ---- system-scope (LLC) accessors. waitcnt lives INSIDE each asm block so the
// register allocator never sees a pending-load destination (R3 bug).
__device__ __forceinline__ float4 ld1q_sys(const float* p) {
  float4 v;
  asm volatile("global_load_dwordx4 %0, %1, off sc0 sc1\n\ts_waitcnt vmcnt(0)"
               : "=v"(v) : "v"(p) : "memory");
  return v;
}
__device__ __forceinline__ void ld4q_sys(const float* p0, const float* p1,
                                         const float* p2, const float* p3,
                                         float4& a, float4& b, float4& c, float4& d) {
  asm volatile(
      "global_load_dwordx4 %0, %4, off sc0 sc1\n\t"
      "global_load_dwordx4 %1, %5, off sc0 sc1\n\t"
      "global_load_dwordx4 %2, %6, off sc0 sc1\n\t"
      "global_load_dwordx4 %3, %7, off sc0 sc1\n\t"
      "s_waitcnt vmcnt(0)"
      : "=&v"(a), "=&v"(b), "=&v"(c), "=&v"(d)
      : "v"(p0), "v"(p1), "v"(p2), "v"(p3) : "memory");
}
__device__ __forceinline__ void ld8q_sys(const float* p0,const float* p1,const float* p2,const float* p3,
                                         const float* p4,const float* p5,const float* p6,const float* p7,
                                         float4& a,float4& b,float4& c,float4& d,
                                         float4& e,float4& f,float4& g,float4& h) {
  asm volatile(
      "global_load_dwordx4 %0, %8, off sc0 sc1\n\t"
      "global_load_dwordx4 %1, %9, off sc0 sc1\n\t"
      "global_load_dwordx4 %2, %10, off sc0 sc1\n\t"
      "global_load_dwordx4 %3, %11, off sc0 sc1\n\t"
      "global_load_dwordx4 %4, %12, off sc0 sc1\n\t"
      "global_load_dwordx4 %5, %13, off sc0 sc1\n\t"
      "global_load_dwordx4 %6, %14, off sc0 sc1\n\t"
      "global_load_dwordx4 %7, %15, off sc0 sc1\n\t"
      "s_waitcnt vmcnt(0)"
      : "=&v"(a),"=&v"(b),"=&v"(c),"=&v"(d),"=&v"(e),"=&v"(f),"=&v"(g),"=&v"(h)
      : "v"(p0),"v"(p1),"v"(p2),"v"(p3),"v"(p4),"v"(p5),"v"(p6),"v"(p7)
      : "memory");
}
__device__ __forceinline__ void st_sys(float* p, float v) {
  asm volatile("global_store_dword %0, %1, off sc0 sc1" :: "v"(p), "v"(v) : "memory");
}
__device__ __forceinline__ u32 ld_sys_u32(const u32* p) {
  u32 r;
  asm volatile("global_load_dword %0, %1, off sc0 sc1\n\ts_waitcnt vmcnt(0)"
               : "=v"(r) : "v"(p) : "memory");
  return r;
}
__device__ __forceinline__ void st_sys_u32(u32* p, u32 v) {
  asm volatile("global_store_dword %0, %1, off sc0 sc1" :: "v"(p), "v"(v) : "memory");
}

// ---- force a float4 to stay resident in registers across the t-loop.
// A volatile asm def cannot be rematerialized by re-loading from memory; the
// allocator must keep it live (or spill to AGPR, which is on-chip and cheap).
#define KEEP4(v) asm volatile("" : "+v"((v).x), "+v"((v).y), "+v"((v).z), "+v"((v).w))

// ---- tree-arrival / flat-release barrier: 16 groups x 16 blocks for arrival
// (spreads atomic contention), single top release word everyone polls.
__device__ __forceinline__ void gridbar(u32* bar, int tid, int blk, u32 ep) {
  asm volatile("s_waitcnt vmcnt(0)" ::: "memory");   // drain this wave's sc stores
  __syncthreads();
  if (tid == 0) {
    const int g = blk & 15;
    u32* cnt  = bar + g*1024;
    u32* tcnt = bar + 16384;
    u32* trel = bar + 16384 + 64;
    const u32 tgt = ep*16u + 15u;
    u32 old = __hip_atomic_fetch_add(cnt, 1u, __ATOMIC_RELAXED, __HIP_MEMORY_SCOPE_AGENT);
    if (old == tgt) {
      u32 told = __hip_atomic_fetch_add(tcnt, 1u, __ATOMIC_RELAXED, __HIP_MEMORY_SCOPE_AGENT);
      if (told == tgt) {
        st_sys_u32(trel, ep + 1u);
      } else {
        while (ld_sys_u32(trel) != ep + 1u) __builtin_amdgcn_s_sleep(2);
      }
    } else {
      while (ld_sys_u32(trel) != ep + 1u) __builtin_amdgcn_s_sleep(2);
    }
  }
  __syncthreads();
}

// ---- wave-64 sum via DPP (VALU pipe, zero DS ops).
// row_shr scan within each 16-lane row -> row sums in lanes 15/31/47/63;
// row_bcast:15 (+rows 1,3) then row_bcast:31 (+row 3) -> total in lane 63.
#define DPP_ADD(v, ctrl, rmask) do { \
  int _t = __builtin_amdgcn_update_dpp(0, __float_as_int(v), (ctrl), (rmask), 0xf, false); \
  (v) += __int_as_float(_t); } while (0)

#define REDUCE64(v) do { \
  DPP_ADD(v, 0x111, 0xf); \
  DPP_ADD(v, 0x112, 0xf); \
  DPP_ADD(v, 0x114, 0xf); \
  DPP_ADD(v, 0x118, 0xf); \
  DPP_ADD(v, 0x142, 0xa); \
  DPP_ADD(v, 0x143, 0x8); } while (0)

// ---------------- prenet
__launch_bounds__(256)
__global__ void prenet_kernel(const float* __restrict__ mels,
                              const float* __restrict__ pW1, const float* __restrict__ pb1,
                              const float* __restrict__ pW2, const float* __restrict__ pb2,
                              float* __restrict__ melpre) {
  __shared__ float mcol[NMEL_];
  __shared__ float pcol[PRE_];
  const int b = blockIdx.x / 30;
  const int tbase = (blockIdx.x % 30) * 10;
  const int tid = threadIdx.x;
  for (int f = 0; f < 10; ++f) {
    const int t = tbase + f;
    if (tid < NMEL_) mcol[tid] = (t == 0) ? 0.0f : mels[(b*NMEL_ + tid)*T_ + (t-1)];
    __syncthreads();
    {
      float a1 = pb1[tid];
      const float* w1 = pW1 + tid*NMEL_;
      for (int m = 0; m < NMEL_; ++m) a1 += w1[m]*mcol[m];
      pcol[tid] = fmaxf(a1, 0.0f);
    }
    __syncthreads();
    {
      float a2 = pb2[tid];
      const float* w2 = pW2 + tid*PRE_;
      for (int d = 0; d < PRE_; d += 4) {
        const float4 wv = *(const float4*)(w2 + d);
        a2 += wv.x*pcol[d] + wv.y*pcol[d+1] + wv.z*pcol[d+2] + wv.w*pcol[d+3];
      }
      melpre[(t*B_ + b)*PRE_ + tid] = fmaxf(a2, 0.0f);
    }
    __syncthreads();
  }
}

// ---------------- init: h states, Weff, barrier region
__launch_bounds__(256)
__global__ void init_kernel(const float* __restrict__ h0,
                            const float* __restrict__ conv1, const float* __restrict__ conv2,
                            float* __restrict__ h1buf, float* __restrict__ h0st,
                            float* __restrict__ weff, u32* __restrict__ bar) {
  const int idx = blockIdx.x*256 + threadIdx.x;
  if (idx < B_*DIM_) {
    const int j = idx & (DIM_-1);
    h0st[idx]  = h0[j];
    h1buf[idx] = h0[DIM_ + j];
  } else if (idx < B_*DIM_ + ATT_*32) {
    const int r = idx - B_*DIM_;
    const int a = r >> 5, k = r & 31;
    float acc = 0.0f;
    if (k < 31) {
      for (int l = 0; l < 32; ++l) acc += conv2[a*32 + l]*conv1[l*31 + k];
    }
    weff[r] = acc;
  } else if (idx < B_*DIM_ + ATT_*32 + BARWORDS) {
    bar[idx - (B_*DIM_ + ATT_*32)] = 0u;
  }
}

// ---------------- l_enc
__launch_bounds__(256)
__global__ void lenc_kernel(const float* __restrict__ enc, const float* __restrict__ Wt,
                            float* __restrict__ lencb) {
  __shared__ float es[4*ENC_];
  const int b = blockIdx.x / 40;
  const int s0 = (blockIdx.x % 40) * 4;
  const int tid = threadIdx.x;
  for (int idx = tid; idx < 4*ENC_; idx += 256) es[idx] = enc[(b*S_ + s0)*ENC_ + idx];
  __syncthreads();
  const int a = tid & 127, sh = tid >> 7;
  const float* w = Wt + a*ENC_;
  for (int p = 0; p < 2; ++p) {
    const int sl = sh*2 + p;
    const float* e = es + sl*ENC_;
    float acc = 0.0f;
    for (int j = 0; j < ENC_; j += 4) {
      const float4 wv = *(const float4*)(w + j);
      acc += wv.x*e[j] + wv.y*e[j+1] + wv.z*e[j+2] + wv.w*e[j+3];
    }
    lencb[(b*S_ + s0 + sl)*ATT_ + a] = acc;
  }
}

// ---------------- persistent decoder
// block blk owns j-columns j0=blk*4 in P2/P3 (LSTM assembly + activation).
// P1: blk<16 attention; blk>=16: own gates0-pre & gates1-pre in LDS (gv0/gv1);
//     blocks 16..79 / 80..143 additionally produce the attn blocks' pre-slots.
// P2: align part of gates0 (weights pinned in regs via KEEP4) + LSTM0 -> h0st
// P3: Wih1@h0 (weights pinned in regs via KEEP4) + LSTM1 -> h1buf; attn blocks
//     also project step t-1.
// launch_bounds(512) w/o min-waves: grid is 1 block/CU, allocator may use the
// full 256 arch-VGPR (+AGPR overflow) budget. KEEP4 makes the pinned weights
// non-rematerializable so the compiler cannot sink the loads back into the loop
// (which is what silently happened in r2/r3).
__launch_bounds__(512)
__global__ void decoder_kernel(
    const float* __restrict__ melpre, const float* __restrict__ lencb,
    const float* __restrict__ weff,
    float* __restrict__ h1buf, float* __restrict__ albuf, float* __restrict__ h0st,
    float* __restrict__ g0pre, float* __restrict__ g1pre, u32* __restrict__ bar,
    const float* __restrict__ enc, const int* __restrict__ tlen,
    const float* __restrict__ Wq, const float* __restrict__ wsc,
    const float* __restrict__ Wih0, const float* __restrict__ Whh0,
    const float* __restrict__ bih0, const float* __restrict__ bhh0,
    const float* __restrict__ Wih1, const float* __restrict__ Whh1,
    const float* __restrict__ bih1, const float* __restrict__ bhh1,
    const float* __restrict__ c0in, const float* __restrict__ projW, const float* __restrict__ projb,
    float* __restrict__ out_mel, float* __restrict__ out_stop, float* __restrict__ out_attn)
{
  extern __shared__ float xt[];
  __shared__ float cum_p[S_ + 30];
  __shared__ float q_s[ATT_];
  __shared__ float spf[S_*4];
  __shared__ float score_s[S_];
  __shared__ float attn_s[S_];
  __shared__ float red_s[1];
  __shared__ float gv[256];    // P2/P3 GEMV reduction
  __shared__ float gv0[256];   // gates0 pre (own rows), persists P1->P2
  __shared__ float gv1[256];   // gates1 pre (own rows), persists P1->P3
  __shared__ float projx[1536];
  __shared__ float wscs[ATT_];

  const int blk = blockIdx.x;
  const int tid = threadIdx.x;
  const int ks = tid & 63;
  const int bgb = ((tid >> 6) & 1)*8;
  const int rg = tid >> 7;
  const int j0 = blk*4;

  // per-block persistent cell state in registers (lanes tid<64)
  float c0r = 0.0f, c1r = 0.0f;
  if (tid < 64) {
    const int j = j0 + (tid >> 4);
    c0r = c0in[j];
    c1r = c0in[DIM_ + j];
  }

  // ---- t-invariant weight pinning: P2 (Wih0 align cols) and P3 (Wih1) rows
  // owned by this thread, held in registers for all 300 steps (96 regs),
  // made non-sinkable via KEEP4.
  float4 wP2[8];    // [ri*2+q], q=0..1 over cols 256..768 of Wih0 row ri*1024+j0+rg
  float4 wP3[16];   // [ri*4+q], q=0..3 over cols 0..1024 of Wih1 row ri*1024+j0+rg
  {
    #pragma unroll
    for (int ri = 0; ri < 4; ++ri) {
      const int n = ri*1024 + j0 + rg;
      #pragma unroll
      for (int q = 0; q < 2; ++q)
        wP2[ri*2+q] = *(const float4*)(Wih0 + n*768 + 256 + q*256 + ks*4);
      #pragma unroll
      for (int q = 0; q < 4; ++q)
        wP3[ri*4+q] = *(const float4*)(Wih1 + n*1024 + q*256 + ks*4);
    }
    #pragma unroll
    for (int i = 0; i < 8; ++i)  KEEP4(wP2[i]);
    #pragma unroll
    for (int i = 0; i < 16; ++i) KEEP4(wP3[i]);
  }

  int mylen = 0;
  if (blk < B_) {
    mylen = tlen[blk];
    for (int i = tid; i < S_ + 30; i += 512) cum_p[i] = 0.0f;
    for (int i = tid; i < 4096; i += 512) xt[WOFF + i] = weff[i];
    if (tid < ATT_) wscs[tid] = wsc[tid];
  }
  __syncthreads();

  u32 ep = 0;

  for (int t = 0; t < T_; ++t) {
    const int prev = t & 1;
    const int cur = prev ^ 1;

    //====================== P1 ======================
    if (blk < B_) {
      const int b = blk;
      // stage [h1prev | alignprev] into projx (used for q now, proj in P3)
      if (tid < 256) {
        float4 v = ld1q_sys(h1buf + prev*B_*DIM_ + b*DIM_ + tid*4);
        *(float4*)(projx + tid*4) = v;
      } else if (tid < 384) {
        const int j = tid - 256;
        float4 v = ld1q_sys(albuf + prev*B_*ENC_ + b*ENC_ + j*4);
        *(float4*)(projx + 1024 + j*4) = v;
      }
      __syncthreads();
      // q = h1prev @ Wq^T
      {
        const int a = tid & 127, part = tid >> 7;
        const float* hp = projx + part*256;
        const float* wq = Wq + a*DIM_ + part*256;
        float acc = 0.0f;
        for (int j = 0; j < 256; j += 4) {
          const float4 wv = *(const float4*)(wq + j);
          const float4 hv = *(const float4*)(hp + j);
          acc += wv.x*hv.x + wv.y*hv.y + wv.z*hv.z + wv.w*hv.w;
        }
        spf[a*4 + part] = acc;
      }
      __syncthreads();
      if (tid < ATT_) q_s[tid] = spf[tid*4] + spf[tid*4+1] + spf[tid*4+2] + spf[tid*4+3];
      __syncthreads();
      // scores
      {
        const int sl = tid & 127, ag = tid >> 7;
        #pragma unroll
        for (int p = 0; p < 2; ++p) {
          const int s = sl + p*128;
          if (s < S_) {
            float cw[31];
            #pragma unroll
            for (int k = 0; k < 31; ++k) cw[k] = cum_p[s + k];
            const float* le = lencb + (b*S_ + s)*ATT_ + ag*32;
            float ps = 0.0f;
            for (int i = 0; i < 32; ++i) {
              const int a = ag*32 + i;
              const float* wk = xt + WOFF + a*32;
              float loc = 0.0f;
              #pragma unroll
              for (int k = 0; k < 31; ++k) loc += wk[k]*cw[k];
              ps += wscs[a]*ftanhf(q_s[a] + le[i] + loc);
            }
            spf[s*4 + ag] = ps;
          }
        }
      }
      __syncthreads();
      if (tid < S_) {
        float sc = spf[tid*4] + spf[tid*4+1] + spf[tid*4+2] + spf[tid*4+3];
        if (tid >= mylen) sc = -1.0e30f;
        score_s[tid] = sc;
      }
      __syncthreads();
      if (tid < 64) {
        float m = -1.0e30f;
        for (int i = tid; i < S_; i += 64) m = fmaxf(m, score_s[i]);
        #pragma unroll
        for (int o = 32; o > 0; o >>= 1) m = fmaxf(m, __shfl_xor(m, o, 64));
        float sum = 0.0f;
        for (int i = tid; i < S_; i += 64) {
          const float e = fexp2f(1.442695041f*(score_s[i] - m));
          score_s[i] = e;
          sum += e;
        }
        #pragma unroll
        for (int o = 32; o > 0; o >>= 1) sum += __shfl_xor(sum, o, 64);
        if (tid == 0) red_s[0] = sum;
      }
      __syncthreads();
      {
        const float inv = 1.0f / red_s[0];
        if (tid < S_) {
          const float av = score_s[tid]*inv;
          attn_s[tid] = av;
          cum_p[15 + tid] += av;
          out_attn[(b*S_ + tid)*T_ + t] = av;
        }
      }
      __syncthreads();
      // align = attn @ enc  -> albuf[cur] (sc)
      {
        const float* eb = enc + (b*S_)*ENC_ + tid;
        float acc = 0.0f;
        for (int s = 0; s < S_; ++s) acc += attn_s[s]*eb[s*ENC_];
        st_sys(albuf + cur*B_*ENC_ + b*ENC_ + tid, acc);
      }
    } else {
      const bool hg0 = (blk >= 16 && blk < 80);
      const bool hg1 = (blk >= 80 && blk < 144);
      const int jx0 = blk - 16;
      const int jx1 = blk - 80;
      // ---- stage [mel | h0prev] tile
      for (int i = tid; i < 1024; i += 512) {
        float4 v = *(const float4*)(melpre + t*4096 + i*4);
        *(float4*)(xt + (i>>6)*XST1 + (i&63)*4) = v;
      }
      {
        float4 r0,r1,r2,r3,r4,r5,r6,r7;
        ld8q_sys(h0st + tid*4, h0st + (tid+512)*4, h0st + (tid+1024)*4, h0st + (tid+1536)*4,
                 h0st + (tid+2048)*4, h0st + (tid+2560)*4, h0st + (tid+3072)*4, h0st + (tid+3584)*4,
                 r0,r1,r2,r3,r4,r5,r6,r7);
        *(float4*)(xt + ((tid       )>>8)*XST1 + 256 + ((tid       )&255)*4) = r0;
        *(float4*)(xt + ((tid + 512 )>>8)*XST1 + 256 + ((tid + 512 )&255)*4) = r1;
        *(float4*)(xt + ((tid + 1024)>>8)*XST1 + 256 + ((tid + 1024)&255)*4) = r2;
        *(float4*)(xt + ((tid + 1536)>>8)*XST1 + 256 + ((tid + 1536)&255)*4) = r3;
        *(float4*)(xt + ((tid + 2048)>>8)*XST1 + 256 + ((tid + 2048)&255)*4) = r4;
        *(float4*)(xt + ((tid + 2560)>>8)*XST1 + 256 + ((tid + 2560)&255)*4) = r5;
        *(float4*)(xt + ((tid + 3072)>>8)*XST1 + 256 + ((tid + 3072)&255)*4) = r6;
        *(float4*)(xt + ((tid + 3584)>>8)*XST1 + 256 + ((tid + 3584)&255)*4) = r7;
      }
      __syncthreads();
      // ---- GEMV-a: gates0 pre = Wih0[:, :256]@mel + Whh0@h0prev (+biases)
      {
        const int nr = hg0 ? 5 : 4;
        int nrow[5];
        #pragma unroll
        for (int ri = 0; ri < 4; ++ri) nrow[ri] = ri*1024 + j0 + rg;
        nrow[4] = rg*1024 + ((jx0 < 64) ? jx0 : 0);
        float acc[5][8];
        #pragma unroll
        for (int ri = 0; ri < 5; ++ri)
          #pragma unroll
          for (int bi = 0; bi < 8; ++bi) acc[ri][bi] = 0.0f;
        { // mel chunk
          const int j = ks*4;
          float4 w4[5];
          #pragma unroll
          for (int ri = 0; ri < 5; ++ri)
            if (ri < nr) w4[ri] = *(const float4*)(Wih0 + nrow[ri]*768 + j);
          #pragma unroll
          for (int bi = 0; bi < 8; ++bi) {
            const float4 xv = *(const float4*)(xt + (bgb+bi)*XST1 + j);
            #pragma unroll
            for (int ri = 0; ri < 5; ++ri)
              if (ri < nr)
                acc[ri][bi] += w4[ri].x*xv.x + w4[ri].y*xv.y + w4[ri].z*xv.z + w4[ri].w*xv.w;
          }
        }
        #pragma unroll
        for (int q = 0; q < 4; ++q) { // h0 chunks
          const int j = q*256 + ks*4;
          float4 w4[5];
          #pragma unroll
          for (int ri = 0; ri < 5; ++ri)
            if (ri < nr) w4[ri] = *(const float4*)(Whh0 + nrow[ri]*1024 + j);
          #pragma unroll
          for (int bi = 0; bi < 8; ++bi) {
            const float4 xv = *(const float4*)(xt + (bgb+bi)*XST1 + 256 + j);
            #pragma unroll
            for (int ri = 0; ri < 5; ++ri)
              if (ri < nr)
                acc[ri][bi] += w4[ri].x*xv.x + w4[ri].y*xv.y + w4[ri].z*xv.z + w4[ri].w*xv.w;
          }
        }
        #pragma unroll
        for (int ri = 0; ri < 5; ++ri)
          if (ri < nr)
            #pragma unroll
            for (int bi = 0; bi < 8; ++bi) {
              float v = acc[ri][bi];
              REDUCE64(v);
              if (ks == 63) {
                const int n = nrow[ri];
                v += bih0[n] + bhh0[n];
                if (ri < 4) gv0[(ri*4 + rg)*16 + (bgb+bi)] = v;
                else        st_sys(g0pre + (bgb+bi)*256 + jx0*4 + rg, v);
              }
            }
      }
      __syncthreads();
      // ---- stage h1prev tile (waited batched LLC load)
      {
        const float* src = h1buf + prev*B_*DIM_;
        float4 r0,r1,r2,r3,r4,r5,r6,r7;
        ld8q_sys(src + tid*4, src + (tid+512)*4, src + (tid+1024)*4, src + (tid+1536)*4,
                 src + (tid+2048)*4, src + (tid+2560)*4, src + (tid+3072)*4, src + (tid+3584)*4,
                 r0,r1,r2,r3,r4,r5,r6,r7);
        *(float4*)(xt + ((tid       )>>8)*XST1 + ((tid       )&255)*4) = r0;
        *(float4*)(xt + ((tid + 512 )>>8)*XST1 + ((tid + 512 )&255)*4) = r1;
        *(float4*)(xt + ((tid + 1024)>>8)*XST1 + ((tid + 1024)&255)*4) = r2;
        *(float4*)(xt + ((tid + 1536)>>8)*XST1 + ((tid + 1536)&255)*4) = r3;
        *(float4*)(xt + ((tid + 2048)>>8)*XST1 + ((tid + 2048)&255)*4) = r4;
        *(float4*)(xt + ((tid + 2560)>>8)*XST1 + ((tid + 2560)&255)*4) = r5;
        *(float4*)(xt + ((tid + 3072)>>8)*XST1 + ((tid + 3072)&255)*4) = r6;
        *(float4*)(xt + ((tid + 3584)>>8)*XST1 + ((tid + 3584)&255)*4) = r7;
      }
      __syncthreads();
      // ---- GEMV-b: gates1 pre = Whh1@h1prev (+biases)
      {
        const int nr = hg1 ? 5 : 4;
        int nrow[5];
        #pragma unroll
        for (int ri = 0; ri < 4; ++ri) nrow[ri] = ri*1024 + j0 + rg;
        nrow[4] = rg*1024 + (hg1 ? jx1 : 0);
        float acc[5][8];
        #pragma unroll
        for (int ri = 0; ri < 5; ++ri)
          #pragma unroll
          for (int bi = 0; bi < 8; ++bi) acc[ri][bi] = 0.0f;
        #pragma unroll
        for (int q = 0; q < 4; ++q) {
          const int j = q*256 + ks*4;
          float4 w4[5];
          #pragma unroll
          for (int ri = 0; ri < 5; ++ri)
            if (ri < nr) w4[ri] = *(const float4*)(Whh1 + nrow[ri]*1024 + j);
          #pragma unroll
          for (int bi = 0; bi < 8; ++bi) {
            const float4 xv = *(const float4*)(xt + (bgb+bi)*XST1 + j);
            #pragma unroll
            for (int ri = 0; ri < 5; ++ri)
              if (ri < nr)
                acc[ri][bi] += w4[ri].x*xv.x + w4[ri].y*xv.y + w4[ri].z*xv.z + w4[ri].w*xv.w;
          }
        }
        #pragma unroll
        for (int ri = 0; ri < 5; ++ri)
          if (ri < nr)
            #pragma unroll
            for (int bi = 0; bi < 8; ++bi) {
              float v = acc[ri][bi];
              REDUCE64(v);
              if (ks == 63) {
                const int n = nrow[ri];
                v += bih1[n] + bhh1[n];
                if (ri < 4) gv1[(ri*4 + rg)*16 + (bgb+bi)] = v;
                else        st_sys(g1pre + (bgb+bi)*256 + jx1*4 + rg, v);
              }
            }
      }
    }
    gridbar(bar, tid, blk, ep); ++ep;

    //====================== P2: gates0 align part (pinned weights) + LSTM0 ======================
    {
      { // stage align tile (waited)
        const float* src = albuf + cur*B_*ENC_;
        float4 r0,r1,r2,r3;
        ld4q_sys(src + tid*4, src + (tid+512)*4, src + (tid+1024)*4, src + (tid+1536)*4,
                 r0,r1,r2,r3);
        *(float4*)(xt + ((tid       )>>7)*XST2 + ((tid       )&127)*4) = r0;
        *(float4*)(xt + ((tid + 512 )>>7)*XST2 + ((tid + 512 )&127)*4) = r1;
        *(float4*)(xt + ((tid + 1024)>>7)*XST2 + ((tid + 1024)&127)*4) = r2;
        *(float4*)(xt + ((tid + 1536)>>7)*XST2 + ((tid + 1536)&127)*4) = r3;
      }
      __syncthreads();
      float acc[4][8];
      #pragma unroll
      for (int ri = 0; ri < 4; ++ri)
        #pragma unroll
        for (int bi = 0; bi < 8; ++bi) acc[ri][bi] = 0.0f;
      #pragma unroll
      for (int q = 0; q < 2; ++q) {
        const int j = q*256 + ks*4;
        #pragma unroll
        for (int bi = 0; bi < 8; ++bi) {
          const float4 xv = *(const float4*)(xt + (bgb+bi)*XST2 + j);
          #pragma unroll
          for (int ri = 0; ri < 4; ++ri)
            acc[ri][bi] += wP2[ri*2+q].x*xv.x + wP2[ri*2+q].y*xv.y + wP2[ri*2+q].z*xv.z + wP2[ri*2+q].w*xv.w;
        }
      }
      #pragma unroll
      for (int ri = 0; ri < 4; ++ri)
        #pragma unroll
        for (int bi = 0; bi < 8; ++bi) {
          float v = acc[ri][bi];
          REDUCE64(v);
          if (ks == 63) gv[(rg*4 + ri)*16 + (bgb+bi)] = v;
        }
      __syncthreads();
      if (tid < 64) {
        const int jl = tid >> 4, bb = tid & 15;
        const int j = j0 + jl;
        float pi, pf, pg, po;
        if (blk < B_) {
          const float4 g4 = ld1q_sys(g0pre + bb*256 + j*4);
          pi = g4.x; pf = g4.y; pg = g4.z; po = g4.w;
        } else {
          pi = gv0[(0*4 + jl)*16 + bb];
          pf = gv0[(1*4 + jl)*16 + bb];
          pg = gv0[(2*4 + jl)*16 + bb];
          po = gv0[(3*4 + jl)*16 + bb];
        }
        const float gi = gv[(jl*4+0)*16 + bb] + pi;
        const float gf = gv[(jl*4+1)*16 + bb] + pf;
        const float gg = gv[(jl*4+2)*16 + bb] + pg;
        const float go = gv[(jl*4+3)*16 + bb] + po;
        const float cn = fsigf(gf)*c0r + fsigf(gi)*ftanhf(gg);
        const float hn = fsigf(go)*ftanhf(cn);
        c0r = cn;
        st_sys(h0st + bb*DIM_ + j, hn);
      }
    }
    gridbar(bar, tid, blk, ep); ++ep;

    //====================== P3: gates1 Wih1@h0 (pinned weights) + LSTM1 (+proj) ======================
    {
      { // stage h0 tile (waited batched)
        float4 r0,r1,r2,r3,r4,r5,r6,r7;
        ld8q_sys(h0st + tid*4, h0st + (tid+512)*4, h0st + (tid+1024)*4, h0st + (tid+1536)*4,
                 h0st + (tid+2048)*4, h0st + (tid+2560)*4, h0st + (tid+3072)*4, h0st + (tid+3584)*4,
                 r0,r1,r2,r3,r4,r5,r6,r7);
        *(float4*)(xt + ((tid       )>>8)*XST3 + ((tid       )&255)*4) = r0;
        *(float4*)(xt + ((tid + 512 )>>8)*XST3 + ((tid + 512 )&255)*4) = r1;
        *(float4*)(xt + ((tid + 1024)>>8)*XST3 + ((tid + 1024)&255)*4) = r2;
        *(float4*)(xt + ((tid + 1536)>>8)*XST3 + ((tid + 1536)&255)*4) = r3;
        *(float4*)(xt + ((tid + 2048)>>8)*XST3 + ((tid + 2048)&255)*4) = r4;
        *(float4*)(xt + ((tid + 2560)>>8)*XST3 + ((tid + 2560)&255)*4) = r5;
        *(float4*)(xt + ((tid + 3072)>>8)*XST3 + ((tid + 3072)&255)*4) = r6;
        *(float4*)(xt + ((tid + 3584)>>8)*XST3 + ((tid + 3584)&255)*4) = r7;
      }
      __syncthreads();
      float acc[4][8];
      #pragma unroll
      for (int ri = 0; ri < 4; ++ri)
        #pragma unroll
        for (int bi = 0; bi < 8; ++bi) acc[ri][bi] = 0.0f;
      #pragma unroll
      for (int q = 0; q < 4; ++q) {
        const int j = q*256 + ks*4;
        #pragma unroll
        for (int bi = 0; bi < 8; ++bi) {
          const float4 xv = *(const float4*)(xt + (bgb+bi)*XST3 + j);
          #pragma unroll
          for (int ri = 0; ri < 4; ++ri)
            acc[ri][bi] += wP3[ri*4+q].x*xv.x + wP3[ri*4+q].y*xv.y + wP3[ri*4+q].z*xv.z + wP3[ri*4+q].w*xv.w;
        }
      }
      #pragma unroll
      for (int ri = 0; ri < 4; ++ri)
        #pragma unroll
        for (int bi = 0; bi < 8; ++bi) {
          float v = acc[ri][bi];
          REDUCE64(v);
          if (ks == 63) gv[(rg*4 + ri)*16 + (bgb+bi)] = v;
        }
      __syncthreads();
      if (tid < 64) {
        const int jl = tid >> 4, bb = tid & 15;
        const int j = j0 + jl;
        float pi, pf, pg, po;
        if (blk < B_) {
          const float4 g4 = ld1q_sys(g1pre + bb*256 + j*4);
          pi = g4.x; pf = g4.y; pg = g4.z; po = g4.w;
        } else {
          pi = gv1[(0*4 + jl)*16 + bb];
          pf = gv1[(1*4 + jl)*16 + bb];
          pg = gv1[(2*4 + jl)*16 + bb];
          po = gv1[(3*4 + jl)*16 + bb];
        }
        const float gi = gv[(jl*4+0)*16 + bb] + pi;
        const float gf = gv[(jl*4+1)*16 + bb] + pf;
        const float gg = gv[(jl*4+2)*16 + bb] + pg;
        const float go = gv[(jl*4+3)*16 + bb] + po;
        const float cn = fsigf(gf)*c1r + fsigf(gi)*ftanhf(gg);
        const float hn = fsigf(go)*ftanhf(cn);
        c1r = cn;
        st_sys(h1buf + cur*B_*DIM_ + bb*DIM_ + j, hn);
      }
      // projection of step t-1 (attn blocks; inputs staged in projx during P1)
      if (blk < B_ && t > 0) {
        const int b = blk;
        const int o = tid >> 2, part = tid & 3;
        if (o < 81) {
          const float* w = projW + o*1536;
          const int jb = part*384;
          float acc2 = 0.0f;
          for (int j = jb; j < jb + 384; j += 4) {
            const float4 wv = *(const float4*)(w + j);
            const float4 xv = *(const float4*)(projx + j);
            acc2 += wv.x*xv.x + wv.y*xv.y + wv.z*xv.z + wv.w*xv.w;
          }
          spf[o*4 + part] = acc2;
        }
        __syncthreads();
        if (tid < 81) {
          const float v = projb[tid] + spf[tid*4] + spf[tid*4+1] + spf[tid*4+2] + spf[tid*4+3];
          if (tid < 80) out_mel[(b*NMEL_ + tid)*T_ + (t-1)] = v;
          else          out_stop[b*T_ + (t-1)] = v;
        }
      }
    }
    gridbar(bar, tid, blk, ep); ++ep;
  }

  // ---- tail projection for t = T_-1 (step-299 h1/align live in slot 0)
  if (blk < B_) {
    const int b = blk;
    if (tid < 256) {
      float4 v = ld1q_sys(h1buf + b*DIM_ + tid*4);
      *(float4*)(projx + tid*4) = v;
    } else if (tid < 384) {
      const int j = tid - 256;
      float4 v = ld1q_sys(albuf + b*ENC_ + j*4);
      *(float4*)(projx + 1024 + j*4) = v;
    }
    __syncthreads();
    const int o = tid >> 2, part = tid & 3;
    if (o < 81) {
      const float* w = projW + o*1536;
      const int jb = part*384;
      float acc = 0.0f;
      for (int j = jb; j < jb + 384; j += 4) {
        const float4 wv = *(const float4*)(w + j);
        const float4 xv = *(const float4*)(projx + j);
        acc += wv.x*xv.x + wv.y*xv.y + wv.z*xv.z + wv.w*xv.w;
      }
      spf[o*4 + part] = acc;
    }
    __syncthreads();
    if (tid < 81) {
      const float v = projb[tid] + spf[tid*4] + spf[tid*4+1] + spf[tid*4+2] + spf[tid*4+3];
      if (tid < 80) out_mel[(b*NMEL_ + tid)*T_ + (T_-1)] = v;
      else          out_stop[b*T_ + (T_-1)] = v;
    }
  }
}

extern "C" void kernel_launch(void* const* d_in, const int* in_sizes, int n_in,
                              void* d_out, int out_size, void* d_ws, size_t ws_size,
                              hipStream_t stream) {
  const float* mels  = (const float*)d_in[0];
  const float* enc   = (const float*)d_in[1];
  const int*   tlen  = (const int*)d_in[2];
  const float* Wt    = (const float*)d_in[3];
  const float* Wq    = (const float*)d_in[4];
  const float* wsc   = (const float*)d_in[5];
  const float* conv1 = (const float*)d_in[6];
  const float* conv2 = (const float*)d_in[7];
  const float* pW1   = (const float*)d_in[8];
  const float* pb1   = (const float*)d_in[9];
  const float* pW2   = (const float*)d_in[10];
  const float* pb2   = (const float*)d_in[11];
  const float* Wih0  = (const float*)d_in[12];
  const float* Whh0  = (const float*)d_in[13];
  const float* bih0  = (const float*)d_in[14];
  const float* bhh0  = (const float*)d_in[15];
  const float* Wih1  = (const float*)d_in[16];
  const float* Whh1  = (const float*)d_in[17];
  const float* bih1  = (const float*)d_in[18];
  const float* bhh1  = (const float*)d_in[19];
  const float* h0    = (const float*)d_in[20];
  const float* c0    = (const float*)d_in[21];
  const float* projW = (const float*)d_in[22];
  const float* projb = (const float*)d_in[23];

  float* ws     = (float*)d_ws;
  float* melpre = ws;                  // 300*16*256   = 1228800
  float* lencb  = melpre + 1228800;    // 16*160*128   = 327680
  float* weff   = lencb + 327680;      // 128*32       = 4096
  float* h1buf  = weff + 4096;         // 2*16*1024    = 32768
  float* albuf  = h1buf + 32768;       // 2*16*512     = 16384
  float* h0st   = albuf + 16384;       // 16*1024      = 16384
  float* g0pre  = h0st + 16384;        // 16*256       = 4096
  float* g1pre  = g0pre + 4096;        // 16*256       = 4096
  u32*   bar    = (u32*)(g1pre + 4096);// 17408 words

  float* out_mel  = (float*)d_out;
  float* out_stop = out_mel + 384000;
  float* out_attn = out_stop + 4800;

  prenet_kernel<<<dim3(480), dim3(256), 0, stream>>>(mels, pW1, pb1, pW2, pb2, melpre);
  init_kernel<<<dim3(160), dim3(256), 0, stream>>>(h0, conv1, conv2, h1buf, h0st, weff, bar);
  lenc_kernel<<<dim3(640), dim3(256), 0, stream>>>(enc, Wt, lencb);

  void* args[] = {
    (void*)&melpre, (void*)&lencb, (void*)&weff, (void*)&h1buf, (void*)&albuf, (void*)&h0st,
    (void*)&g0pre, (void*)&g1pre, (void*)&bar,
    (void*)&enc, (void*)&tlen, (void*)&Wq, (void*)&wsc,
    (void*)&Wih0, (void*)&Whh0, (void*)&bih0, (void*)&bhh0,
    (void*)&Wih1, (void*)&Whh1, (void*)&bih1, (void*)&bhh1,
    (void*)&c0, (void*)&projW, (void*)&projb,
    (void*)&out_mel, (void*)&out_stop, (void*)&out_attn
  };
  hipLaunchCooperativeKernel((const void*)decoder_kernel, dim3(256), dim3(512),
                             args, (unsigned int)(XTOT*sizeof(float)), stream);
}

// Round 5
// 47968.277 us; speedup vs baseline: 1.4489x; 1.4489x over previous
//
#include <hip/hip_runtime.h>

#define T_    300
#define B_    16
#define S_    160
#define NMEL_ 80
#define PRE_  256
#define ENC_  512
#define ATT_  128
#define DIM_  1024

#define XST1  1288     // P1 tile stride (mel 256 + h0 1024 + pad 8); rows end at 20600
#define XST2  520      // P2 align tile stride (ends 8320)
#define XST3  1032     // P3 h0 tile stride (ends 16504)
#define WOFF  16512    // attn blocks: weff copy [16512..20608) — above P2/P3 staging reach
#define WLDS  20608    // compute blocks: pinned Wih1 rows, 16x1024 = 16384 floats
#define AOFF  36992    // attn blocks: persistent arrays (cum_p, projx, wscs)
#define XTOT  38848    // dynamic LDS floats (155.4 KB)
#define BARWORDS 17408

typedef unsigned int u32;

__device__ __forceinline__ float fexp2f(float x) { return __builtin_amdgcn_exp2f(x); }
__device__ __forceinline__ float fsigf(float x)  { return 1.0f / (1.0f + fexp2f(-1.442695041f * x)); }
__device__ __forceinline__ float ftanhf(float x) {
  float xc = fminf(fmaxf(x, -15.0f), 15.0f);
  float e = fexp2f(2.885390082f * xc);
  return (e - 1.0f) / (e + 1.0f);
}

// ---- system-scope (LLC) accessors. waitcnt lives INSIDE each asm block so the
// register allocator never sees a pending-load destination (R3 bug).
__device__ __forceinline__ float4 ld1q_sys(const float* p) {
  float4 v;
  asm volatile("global_load_dwordx4 %0, %1, off sc0 sc1\n\ts_waitcnt vmcnt(0)"
               : "=v"(v) : "v"(p) : "memory");
  return v;
}
__device__ __forceinline__ void ld4q_sys(const float* p0, const float* p1,
                                         const float* p2, const float* p3,
                                         float4& a, float4& b, float4& c, float4& d) {
  asm volatile(
      "global_load_dwordx4 %0, %4, off sc0 sc1\n\t"
      "global_load_dwordx4 %1, %5, off sc0 sc1\n\t"
      "global_load_dwordx4 %2, %6, off sc0 sc1\n\t"
      "global_load_dwordx4 %3, %7, off sc0 sc1\n\t"
      "s_waitcnt vmcnt(0)"
      : "=&v"(a), "=&v"(b), "=&v"(c), "=&v"(d)
      : "v"(p0), "v"(p1), "v"(p2), "v"(p3) : "memory");
}
__device__ __forceinline__ void ld8q_sys(const float* p0,const float* p1,const float* p2,const float* p3,
                                         const float* p4,const float* p5,const float* p6,const float* p7,
                                         float4& a,float4& b,float4& c,float4& d,
                                         float4& e,float4& f,float4& g,float4& h) {
  asm volatile(
      "global_load_dwordx4 %0, %8, off sc0 sc1\n\t"
      "global_load_dwordx4 %1, %9, off sc0 sc1\n\t"
      "global_load_dwordx4 %2, %10, off sc0 sc1\n\t"
      "global_load_dwordx4 %3, %11, off sc0 sc1\n\t"
      "global_load_dwordx4 %4, %12, off sc0 sc1\n\t"
      "global_load_dwordx4 %5, %13, off sc0 sc1\n\t"
      "global_load_dwordx4 %6, %14, off sc0 sc1\n\t"
      "global_load_dwordx4 %7, %15, off sc0 sc1\n\t"
      "s_waitcnt vmcnt(0)"
      : "=&v"(a),"=&v"(b),"=&v"(c),"=&v"(d),"=&v"(e),"=&v"(f),"=&v"(g),"=&v"(h)
      : "v"(p0),"v"(p1),"v"(p2),"v"(p3),"v"(p4),"v"(p5),"v"(p6),"v"(p7)
      : "memory");
}
__device__ __forceinline__ void st_sys(float* p, float v) {
  asm volatile("global_store_dword %0, %1, off sc0 sc1" :: "v"(p), "v"(v) : "memory");
}
__device__ __forceinline__ u32 ld_sys_u32(const u32* p) {
  u32 r;
  asm volatile("global_load_dword %0, %1, off sc0 sc1\n\ts_waitcnt vmcnt(0)"
               : "=v"(r) : "v"(p) : "memory");
  return r;
}
__device__ __forceinline__ void st_sys_u32(u32* p, u32 v) {
  asm volatile("global_store_dword %0, %1, off sc0 sc1" :: "v"(p), "v"(v) : "memory");
}

// ---- tree-arrival / flat-release barrier: 16 groups x 16 blocks for arrival
// (spreads atomic contention), single top release word everyone polls.
__device__ __forceinline__ void gridbar(u32* bar, int tid, int blk, u32 ep) {
  asm volatile("s_waitcnt vmcnt(0)" ::: "memory");   // drain this wave's sc stores
  __syncthreads();
  if (tid == 0) {
    const int g = blk & 15;
    u32* cnt  = bar + g*1024;
    u32* tcnt = bar + 16384;
    u32* trel = bar + 16384 + 64;
    const u32 tgt = ep*16u + 15u;
    u32 old = __hip_atomic_fetch_add(cnt, 1u, __ATOMIC_RELAXED, __HIP_MEMORY_SCOPE_AGENT);
    if (old == tgt) {
      u32 told = __hip_atomic_fetch_add(tcnt, 1u, __ATOMIC_RELAXED, __HIP_MEMORY_SCOPE_AGENT);
      if (told == tgt) {
        st_sys_u32(trel, ep + 1u);
      } else {
        while (ld_sys_u32(trel) != ep + 1u) __builtin_amdgcn_s_sleep(2);
      }
    } else {
      while (ld_sys_u32(trel) != ep + 1u) __builtin_amdgcn_s_sleep(2);
    }
  }
  __syncthreads();
}

// ---- wave-64 sum via DPP (VALU pipe, zero DS ops).
// row_shr scan within each 16-lane row -> row sums in lanes 15/31/47/63;
// row_bcast:15 (+rows 1,3) then row_bcast:31 (+row 3) -> total in lane 63.
#define DPP_ADD(v, ctrl, rmask) do { \
  int _t = __builtin_amdgcn_update_dpp(0, __float_as_int(v), (ctrl), (rmask), 0xf, false); \
  (v) += __int_as_float(_t); } while (0)

#define REDUCE64(v) do { \
  DPP_ADD(v, 0x111, 0xf); \
  DPP_ADD(v, 0x112, 0xf); \
  DPP_ADD(v, 0x114, 0xf); \
  DPP_ADD(v, 0x118, 0xf); \
  DPP_ADD(v, 0x142, 0xa); \
  DPP_ADD(v, 0x143, 0x8); } while (0)

// ---------------- prenet
__launch_bounds__(256)
__global__ void prenet_kernel(const float* __restrict__ mels,
                              const float* __restrict__ pW1, const float* __restrict__ pb1,
                              const float* __restrict__ pW2, const float* __restrict__ pb2,
                              float* __restrict__ melpre) {
  __shared__ float mcol[NMEL_];
  __shared__ float pcol[PRE_];
  const int b = blockIdx.x / 30;
  const int tbase = (blockIdx.x % 30) * 10;
  const int tid = threadIdx.x;
  for (int f = 0; f < 10; ++f) {
    const int t = tbase + f;
    if (tid < NMEL_) mcol[tid] = (t == 0) ? 0.0f : mels[(b*NMEL_ + tid)*T_ + (t-1)];
    __syncthreads();
    {
      float a1 = pb1[tid];
      const float* w1 = pW1 + tid*NMEL_;
      for (int m = 0; m < NMEL_; ++m) a1 += w1[m]*mcol[m];
      pcol[tid] = fmaxf(a1, 0.0f);
    }
    __syncthreads();
    {
      float a2 = pb2[tid];
      const float* w2 = pW2 + tid*PRE_;
      for (int d = 0; d < PRE_; d += 4) {
        const float4 wv = *(const float4*)(w2 + d);
        a2 += wv.x*pcol[d] + wv.y*pcol[d+1] + wv.z*pcol[d+2] + wv.w*pcol[d+3];
      }
      melpre[(t*B_ + b)*PRE_ + tid] = fmaxf(a2, 0.0f);
    }
    __syncthreads();
  }
}

// ---------------- init: h states, Weff, barrier region
__launch_bounds__(256)
__global__ void init_kernel(const float* __restrict__ h0,
                            const float* __restrict__ conv1, const float* __restrict__ conv2,
                            float* __restrict__ h1buf, float* __restrict__ h0st,
                            float* __restrict__ weff, u32* __restrict__ bar) {
  const int idx = blockIdx.x*256 + threadIdx.x;
  if (idx < B_*DIM_) {
    const int j = idx & (DIM_-1);
    h0st[idx]  = h0[j];
    h1buf[idx] = h0[DIM_ + j];
  } else if (idx < B_*DIM_ + ATT_*32) {
    const int r = idx - B_*DIM_;
    const int a = r >> 5, k = r & 31;
    float acc = 0.0f;
    if (k < 31) {
      for (int l = 0; l < 32; ++l) acc += conv2[a*32 + l]*conv1[l*31 + k];
    }
    weff[r] = acc;
  } else if (idx < B_*DIM_ + ATT_*32 + BARWORDS) {
    bar[idx - (B_*DIM_ + ATT_*32)] = 0u;
  }
}

// ---------------- l_enc
__launch_bounds__(256)
__global__ void lenc_kernel(const float* __restrict__ enc, const float* __restrict__ Wt,
                            float* __restrict__ lencb) {
  __shared__ float es[4*ENC_];
  const int b = blockIdx.x / 40;
  const int s0 = (blockIdx.x % 40) * 4;
  const int tid = threadIdx.x;
  for (int idx = tid; idx < 4*ENC_; idx += 256) es[idx] = enc[(b*S_ + s0)*ENC_ + idx];
  __syncthreads();
  const int a = tid & 127, sh = tid >> 7;
  const float* w = Wt + a*ENC_;
  for (int p = 0; p < 2; ++p) {
    const int sl = sh*2 + p;
    const float* e = es + sl*ENC_;
    float acc = 0.0f;
    for (int j = 0; j < ENC_; j += 4) {
      const float4 wv = *(const float4*)(w + j);
      acc += wv.x*e[j] + wv.y*e[j+1] + wv.z*e[j+2] + wv.w*e[j+3];
    }
    lencb[(b*S_ + s0 + sl)*ATT_ + a] = acc;
  }
}

// ---------------- persistent decoder
// block blk owns j-columns j0=blk*4 in P2/P3 (LSTM assembly + activation).
// P1: blk<16 attention + projection of step t-1; blk>=16: gates0-pre &
//     gates1-pre (r1 GEMV form). P2: align part of gates0 + LSTM0 -> h0st.
// P3: Wih1@h0 + LSTM1 -> h1buf. Compute blocks read their Wih1 rows from an
//     LDS-pinned copy (loaded once; 64 KB); attn blocks stream Wih1 as before
//     but no longer carry the projection, so P3 is balanced.
// LDS overlays (per-block, role-dependent):
//   compute: x-tile [0..20608) | wP3 [20608..36992)
//   attn:    staging [0..16512) + P1-transient {q_s,spf,score_s,attn_s} at [0..1088)
//            | weff [16512..20608) | cum_p/projx/wscs [36992..38848)
__launch_bounds__(512, 2)
__global__ void decoder_kernel(
    const float* __restrict__ melpre, const float* __restrict__ lencb,
    const float* __restrict__ weff,
    float* __restrict__ h1buf, float* __restrict__ albuf, float* __restrict__ h0st,
    float* __restrict__ g0pre, float* __restrict__ g1pre, u32* __restrict__ bar,
    const float* __restrict__ enc, const int* __restrict__ tlen,
    const float* __restrict__ Wq, const float* __restrict__ wsc,
    const float* __restrict__ Wih0, const float* __restrict__ Whh0,
    const float* __restrict__ bih0, const float* __restrict__ bhh0,
    const float* __restrict__ Wih1, const float* __restrict__ Whh1,
    const float* __restrict__ bih1, const float* __restrict__ bhh1,
    const float* __restrict__ c0in, const float* __restrict__ projW, const float* __restrict__ projb,
    float* __restrict__ out_mel, float* __restrict__ out_stop, float* __restrict__ out_attn)
{
  extern __shared__ float xt[];
  __shared__ float red_s[1];
  __shared__ float gv[256];    // P2/P3 GEMV reduction
  __shared__ float gv0[256];   // gates0 pre (own rows), persists P1->P2
  __shared__ float gv1[256];   // gates1 pre (own rows), persists P1->P3

  // attn-block overlays into dynamic LDS (compute blocks never touch these)
  float* const q_s     = xt;                 // [128]  P1 transient
  float* const spf     = xt + 128;           // [640]  P1 transient (scores, proj)
  float* const score_s = xt + 768;           // [160]  P1 transient
  float* const attn_s  = xt + 928;           // [160]  P1 transient
  float* const cum_p   = xt + AOFF;          // [190]  persistent
  float* const projx   = xt + AOFF + 192;    // [1536] persistent within step
  float* const wscs    = xt + AOFF + 1728;   // [128]  persistent

  const int blk = blockIdx.x;
  const int tid = threadIdx.x;
  const int ks = tid & 63;
  const int bgb = ((tid >> 6) & 1)*8;
  const int rg = tid >> 7;
  const int j0 = blk*4;

  // per-block persistent cell state in registers (lanes tid<64)
  float c0r = 0.0f, c1r = 0.0f;
  if (tid < 64) {
    const int j = j0 + (tid >> 4);
    c0r = c0in[j];
    c1r = c0in[DIM_ + j];
  }
  int mylen = 0;
  if (blk < B_) {
    mylen = tlen[blk];
    for (int i = tid; i < S_ + 30; i += 512) cum_p[i] = 0.0f;
    for (int i = tid; i < 4096; i += 512) xt[WOFF + i] = weff[i];
    if (tid < ATT_) wscs[tid] = wsc[tid];
  } else {
    // pin this block's Wih1 rows (16 rows x 1024 cols) into LDS, chunked so
    // lane ks reads chunk c at [c*256 + ks*4] conflict-free in P3.
    // chunk c = (ri*4 + rg)*4 + q, row = ri*1024 + j0 + rg, cols q*256..+255.
    for (int i = tid; i < 4096; i += 512) {
      const int c = i >> 6, l = i & 63;
      const int ri = c >> 4, rgw = (c >> 2) & 3, q = c & 3;
      *(float4*)(xt + WLDS + c*256 + l*4) =
          *(const float4*)(Wih1 + (ri*1024 + j0 + rgw)*1024 + q*256 + l*4);
    }
  }
  __syncthreads();

  u32 ep = 0;

  for (int t = 0; t < T_; ++t) {
    const int prev = t & 1;
    const int cur = prev ^ 1;

    //====================== P1 ======================
    if (blk < B_) {
      const int b = blk;
      // stage [h1prev | alignprev] into projx (used for q and proj below)
      if (tid < 256) {
        float4 v = ld1q_sys(h1buf + prev*B_*DIM_ + b*DIM_ + tid*4);
        *(float4*)(projx + tid*4) = v;
      } else if (tid < 384) {
        const int j = tid - 256;
        float4 v = ld1q_sys(albuf + prev*B_*ENC_ + b*ENC_ + j*4);
        *(float4*)(projx + 1024 + j*4) = v;
      }
      __syncthreads();
      // q = h1prev @ Wq^T
      {
        const int a = tid & 127, part = tid >> 7;
        const float* hp = projx + part*256;
        const float* wq = Wq + a*DIM_ + part*256;
        float acc = 0.0f;
        for (int j = 0; j < 256; j += 4) {
          const float4 wv = *(const float4*)(wq + j);
          const float4 hv = *(const float4*)(hp + j);
          acc += wv.x*hv.x + wv.y*hv.y + wv.z*hv.z + wv.w*hv.w;
        }
        spf[a*4 + part] = acc;
      }
      __syncthreads();
      if (tid < ATT_) q_s[tid] = spf[tid*4] + spf[tid*4+1] + spf[tid*4+2] + spf[tid*4+3];
      __syncthreads();
      // scores
      {
        const int sl = tid & 127, ag = tid >> 7;
        #pragma unroll
        for (int p = 0; p < 2; ++p) {
          const int s = sl + p*128;
          if (s < S_) {
            float cw[31];
            #pragma unroll
            for (int k = 0; k < 31; ++k) cw[k] = cum_p[s + k];
            const float* le = lencb + (b*S_ + s)*ATT_ + ag*32;
            float ps = 0.0f;
            for (int i = 0; i < 32; ++i) {
              const int a = ag*32 + i;
              const float* wk = xt + WOFF + a*32;
              float loc = 0.0f;
              #pragma unroll
              for (int k = 0; k < 31; ++k) loc += wk[k]*cw[k];
              ps += wscs[a]*ftanhf(q_s[a] + le[i] + loc);
            }
            spf[s*4 + ag] = ps;
          }
        }
      }
      __syncthreads();
      if (tid < S_) {
        float sc = spf[tid*4] + spf[tid*4+1] + spf[tid*4+2] + spf[tid*4+3];
        if (tid >= mylen) sc = -1.0e30f;
        score_s[tid] = sc;
      }
      __syncthreads();
      if (tid < 64) {
        float m = -1.0e30f;
        for (int i = tid; i < S_; i += 64) m = fmaxf(m, score_s[i]);
        #pragma unroll
        for (int o = 32; o > 0; o >>= 1) m = fmaxf(m, __shfl_xor(m, o, 64));
        float sum = 0.0f;
        for (int i = tid; i < S_; i += 64) {
          const float e = fexp2f(1.442695041f*(score_s[i] - m));
          score_s[i] = e;
          sum += e;
        }
        #pragma unroll
        for (int o = 32; o > 0; o >>= 1) sum += __shfl_xor(sum, o, 64);
        if (tid == 0) red_s[0] = sum;
      }
      __syncthreads();
      {
        const float inv = 1.0f / red_s[0];
        if (tid < S_) {
          const float av = score_s[tid]*inv;
          attn_s[tid] = av;
          cum_p[15 + tid] += av;
          out_attn[(b*S_ + tid)*T_ + t] = av;
        }
      }
      __syncthreads();
      // align = attn @ enc  -> albuf[cur] (sc)
      {
        const float* eb = enc + (b*S_)*ENC_ + tid;
        float acc = 0.0f;
        for (int s = 0; s < S_; ++s) acc += attn_s[s]*eb[s*ENC_];
        st_sys(albuf + cur*B_*ENC_ + b*ENC_ + tid, acc);
      }
      // projection of step t-1 (moved here from P3; inputs are in projx).
      if (t > 0) {
        const int o = tid >> 2, part = tid & 3;
        if (o < 81) {
          const float* w = projW + o*1536;
          const int jb = part*384;
          float acc2 = 0.0f;
          for (int j = jb; j < jb + 384; j += 4) {
            const float4 wv = *(const float4*)(w + j);
            const float4 xv = *(const float4*)(projx + j);
            acc2 += wv.x*xv.x + wv.y*xv.y + wv.z*xv.z + wv.w*xv.w;
          }
          spf[o*4 + part] = acc2;
        }
        __syncthreads();
        if (tid < 81) {
          const float v = projb[tid] + spf[tid*4] + spf[tid*4+1] + spf[tid*4+2] + spf[tid*4+3];
          if (tid < 80) out_mel[(b*NMEL_ + tid)*T_ + (t-1)] = v;
          else          out_stop[b*T_ + (t-1)] = v;
        }
      }
    } else {
      const bool hg0 = (blk >= 16 && blk < 80);
      const bool hg1 = (blk >= 80 && blk < 144);
      const int jx0 = blk - 16;
      const int jx1 = blk - 80;
      // ---- stage [mel | h0prev] tile
      for (int i = tid; i < 1024; i += 512) {
        float4 v = *(const float4*)(melpre + t*4096 + i*4);
        *(float4*)(xt + (i>>6)*XST1 + (i&63)*4) = v;
      }
      {
        float4 r0,r1,r2,r3,r4,r5,r6,r7;
        ld8q_sys(h0st + tid*4, h0st + (tid+512)*4, h0st + (tid+1024)*4, h0st + (tid+1536)*4,
                 h0st + (tid+2048)*4, h0st + (tid+2560)*4, h0st + (tid+3072)*4, h0st + (tid+3584)*4,
                 r0,r1,r2,r3,r4,r5,r6,r7);
        *(float4*)(xt + ((tid       )>>8)*XST1 + 256 + ((tid       )&255)*4) = r0;
        *(float4*)(xt + ((tid + 512 )>>8)*XST1 + 256 + ((tid + 512 )&255)*4) = r1;
        *(float4*)(xt + ((tid + 1024)>>8)*XST1 + 256 + ((tid + 1024)&255)*4) = r2;
        *(float4*)(xt + ((tid + 1536)>>8)*XST1 + 256 + ((tid + 1536)&255)*4) = r3;
        *(float4*)(xt + ((tid + 2048)>>8)*XST1 + 256 + ((tid + 2048)&255)*4) = r4;
        *(float4*)(xt + ((tid + 2560)>>8)*XST1 + 256 + ((tid + 2560)&255)*4) = r5;
        *(float4*)(xt + ((tid + 3072)>>8)*XST1 + 256 + ((tid + 3072)&255)*4) = r6;
        *(float4*)(xt + ((tid + 3584)>>8)*XST1 + 256 + ((tid + 3584)&255)*4) = r7;
      }
      __syncthreads();
      // ---- GEMV-a: gates0 pre = Wih0[:, :256]@mel + Whh0@h0prev (+biases)
      {
        const int nr = hg0 ? 5 : 4;
        int nrow[5];
        #pragma unroll
        for (int ri = 0; ri < 4; ++ri) nrow[ri] = ri*1024 + j0 + rg;
        nrow[4] = rg*1024 + ((jx0 < 64) ? jx0 : 0);
        float acc[5][8];
        #pragma unroll
        for (int ri = 0; ri < 5; ++ri)
          #pragma unroll
          for (int bi = 0; bi < 8; ++bi) acc[ri][bi] = 0.0f;
        { // mel chunk
          const int j = ks*4;
          float4 w4[5];
          #pragma unroll
          for (int ri = 0; ri < 5; ++ri)
            if (ri < nr) w4[ri] = *(const float4*)(Wih0 + nrow[ri]*768 + j);
          #pragma unroll
          for (int bi = 0; bi < 8; ++bi) {
            const float4 xv = *(const float4*)(xt + (bgb+bi)*XST1 + j);
            #pragma unroll
            for (int ri = 0; ri < 5; ++ri)
              if (ri < nr)
                acc[ri][bi] += w4[ri].x*xv.x + w4[ri].y*xv.y + w4[ri].z*xv.z + w4[ri].w*xv.w;
          }
        }
        #pragma unroll
        for (int q = 0; q < 4; ++q) { // h0 chunks
          const int j = q*256 + ks*4;
          float4 w4[5];
          #pragma unroll
          for (int ri = 0; ri < 5; ++ri)
            if (ri < nr) w4[ri] = *(const float4*)(Whh0 + nrow[ri]*1024 + j);
          #pragma unroll
          for (int bi = 0; bi < 8; ++bi) {
            const float4 xv = *(const float4*)(xt + (bgb+bi)*XST1 + 256 + j);
            #pragma unroll
            for (int ri = 0; ri < 5; ++ri)
              if (ri < nr)
                acc[ri][bi] += w4[ri].x*xv.x + w4[ri].y*xv.y + w4[ri].z*xv.z + w4[ri].w*xv.w;
          }
        }
        #pragma unroll
        for (int ri = 0; ri < 5; ++ri)
          if (ri < nr)
            #pragma unroll
            for (int bi = 0; bi < 8; ++bi) {
              float v = acc[ri][bi];
              REDUCE64(v);
              if (ks == 63) {
                const int n = nrow[ri];
                v += bih0[n] + bhh0[n];
                if (ri < 4) gv0[(ri*4 + rg)*16 + (bgb+bi)] = v;
                else        st_sys(g0pre + (bgb+bi)*256 + jx0*4 + rg, v);
              }
            }
      }
      __syncthreads();
      // ---- stage h1prev tile (waited batched LLC load)
      {
        const float* src = h1buf + prev*B_*DIM_;
        float4 r0,r1,r2,r3,r4,r5,r6,r7;
        ld8q_sys(src + tid*4, src + (tid+512)*4, src + (tid+1024)*4, src + (tid+1536)*4,
                 src + (tid+2048)*4, src + (tid+2560)*4, src + (tid+3072)*4, src + (tid+3584)*4,
                 r0,r1,r2,r3,r4,r5,r6,r7);
        *(float4*)(xt + ((tid       )>>8)*XST1 + ((tid       )&255)*4) = r0;
        *(float4*)(xt + ((tid + 512 )>>8)*XST1 + ((tid + 512 )&255)*4) = r1;
        *(float4*)(xt + ((tid + 1024)>>8)*XST1 + ((tid + 1024)&255)*4) = r2;
        *(float4*)(xt + ((tid + 1536)>>8)*XST1 + ((tid + 1536)&255)*4) = r3;
        *(float4*)(xt + ((tid + 2048)>>8)*XST1 + ((tid + 2048)&255)*4) = r4;
        *(float4*)(xt + ((tid + 2560)>>8)*XST1 + ((tid + 2560)&255)*4) = r5;
        *(float4*)(xt + ((tid + 3072)>>8)*XST1 + ((tid + 3072)&255)*4) = r6;
        *(float4*)(xt + ((tid + 3584)>>8)*XST1 + ((tid + 3584)&255)*4) = r7;
      }
      __syncthreads();
      // ---- GEMV-b: gates1 pre = Whh1@h1prev (+biases)
      {
        const int nr = hg1 ? 5 : 4;
        int nrow[5];
        #pragma unroll
        for (int ri = 0; ri < 4; ++ri) nrow[ri] = ri*1024 + j0 + rg;
        nrow[4] = rg*1024 + (hg1 ? jx1 : 0);
        float acc[5][8];
        #pragma unroll
        for (int ri = 0; ri < 5; ++ri)
          #pragma unroll
          for (int bi = 0; bi < 8; ++bi) acc[ri][bi] = 0.0f;
        #pragma unroll
        for (int q = 0; q < 4; ++q) {
          const int j = q*256 + ks*4;
          float4 w4[5];
          #pragma unroll
          for (int ri = 0; ri < 5; ++ri)
            if (ri < nr) w4[ri] = *(const float4*)(Whh1 + nrow[ri]*1024 + j);
          #pragma unroll
          for (int bi = 0; bi < 8; ++bi) {
            const float4 xv = *(const float4*)(xt + (bgb+bi)*XST1 + j);
            #pragma unroll
            for (int ri = 0; ri < 5; ++ri)
              if (ri < nr)
                acc[ri][bi] += w4[ri].x*xv.x + w4[ri].y*xv.y + w4[ri].z*xv.z + w4[ri].w*xv.w;
          }
        }
        #pragma unroll
        for (int ri = 0; ri < 5; ++ri)
          if (ri < nr)
            #pragma unroll
            for (int bi = 0; bi < 8; ++bi) {
              float v = acc[ri][bi];
              REDUCE64(v);
              if (ks == 63) {
                const int n = nrow[ri];
                v += bih1[n] + bhh1[n];
                if (ri < 4) gv1[(ri*4 + rg)*16 + (bgb+bi)] = v;
                else        st_sys(g1pre + (bgb+bi)*256 + jx1*4 + rg, v);
              }
            }
      }
    }
    gridbar(bar, tid, blk, ep); ++ep;

    //====================== P2: gates0 align part + LSTM0 ======================
    {
      { // stage align tile (waited)
        const float* src = albuf + cur*B_*ENC_;
        float4 r0,r1,r2,r3;
        ld4q_sys(src + tid*4, src + (tid+512)*4, src + (tid+1024)*4, src + (tid+1536)*4,
                 r0,r1,r2,r3);
        *(float4*)(xt + ((tid       )>>7)*XST2 + ((tid       )&127)*4) = r0;
        *(float4*)(xt + ((tid + 512 )>>7)*XST2 + ((tid + 512 )&127)*4) = r1;
        *(float4*)(xt + ((tid + 1024)>>7)*XST2 + ((tid + 1024)&127)*4) = r2;
        *(float4*)(xt + ((tid + 1536)>>7)*XST2 + ((tid + 1536)&127)*4) = r3;
      }
      __syncthreads();
      float acc[4][8];
      #pragma unroll
      for (int ri = 0; ri < 4; ++ri)
        #pragma unroll
        for (int bi = 0; bi < 8; ++bi) acc[ri][bi] = 0.0f;
      #pragma unroll
      for (int q = 0; q < 2; ++q) {
        const int j = q*256 + ks*4;
        float4 w4[4];
        #pragma unroll
        for (int ri = 0; ri < 4; ++ri)
          w4[ri] = *(const float4*)(Wih0 + (ri*1024 + j0 + rg)*768 + 256 + j);
        #pragma unroll
        for (int bi = 0; bi < 8; ++bi) {
          const float4 xv = *(const float4*)(xt + (bgb+bi)*XST2 + j);
          #pragma unroll
          for (int ri = 0; ri < 4; ++ri)
            acc[ri][bi] += w4[ri].x*xv.x + w4[ri].y*xv.y + w4[ri].z*xv.z + w4[ri].w*xv.w;
        }
      }
      #pragma unroll
      for (int ri = 0; ri < 4; ++ri)
        #pragma unroll
        for (int bi = 0; bi < 8; ++bi) {
          float v = acc[ri][bi];
          REDUCE64(v);
          if (ks == 63) gv[(rg*4 + ri)*16 + (bgb+bi)] = v;
        }
      __syncthreads();
      if (tid < 64) {
        const int jl = tid >> 4, bb = tid & 15;
        const int j = j0 + jl;
        float pi, pf, pg, po;
        if (blk < B_) {
          const float4 g4 = ld1q_sys(g0pre + bb*256 + j*4);
          pi = g4.x; pf = g4.y; pg = g4.z; po = g4.w;
        } else {
          pi = gv0[(0*4 + jl)*16 + bb];
          pf = gv0[(1*4 + jl)*16 + bb];
          pg = gv0[(2*4 + jl)*16 + bb];
          po = gv0[(3*4 + jl)*16 + bb];
        }
        const float gi = gv[(jl*4+0)*16 + bb] + pi;
        const float gf = gv[(jl*4+1)*16 + bb] + pf;
        const float gg = gv[(jl*4+2)*16 + bb] + pg;
        const float go = gv[(jl*4+3)*16 + bb] + po;
        const float cn = fsigf(gf)*c0r + fsigf(gi)*ftanhf(gg);
        const float hn = fsigf(go)*ftanhf(cn);
        c0r = cn;
        st_sys(h0st + bb*DIM_ + j, hn);
      }
    }
    gridbar(bar, tid, blk, ep); ++ep;

    //====================== P3: gates1 Wih1@h0 + LSTM1 ======================
    {
      { // stage h0 tile (waited batched)
        float4 r0,r1,r2,r3,r4,r5,r6,r7;
        ld8q_sys(h0st + tid*4, h0st + (tid+512)*4, h0st + (tid+1024)*4, h0st + (tid+1536)*4,
                 h0st + (tid+2048)*4, h0st + (tid+2560)*4, h0st + (tid+3072)*4, h0st + (tid+3584)*4,
                 r0,r1,r2,r3,r4,r5,r6,r7);
        *(float4*)(xt + ((tid       )>>8)*XST3 + ((tid       )&255)*4) = r0;
        *(float4*)(xt + ((tid + 512 )>>8)*XST3 + ((tid + 512 )&255)*4) = r1;
        *(float4*)(xt + ((tid + 1024)>>8)*XST3 + ((tid + 1024)&255)*4) = r2;
        *(float4*)(xt + ((tid + 1536)>>8)*XST3 + ((tid + 1536)&255)*4) = r3;
        *(float4*)(xt + ((tid + 2048)>>8)*XST3 + ((tid + 2048)&255)*4) = r4;
        *(float4*)(xt + ((tid + 2560)>>8)*XST3 + ((tid + 2560)&255)*4) = r5;
        *(float4*)(xt + ((tid + 3072)>>8)*XST3 + ((tid + 3072)&255)*4) = r6;
        *(float4*)(xt + ((tid + 3584)>>8)*XST3 + ((tid + 3584)&255)*4) = r7;
      }
      __syncthreads();
      float acc[4][8];
      #pragma unroll
      for (int ri = 0; ri < 4; ++ri)
        #pragma unroll
        for (int bi = 0; bi < 8; ++bi) acc[ri][bi] = 0.0f;
      #pragma unroll
      for (int q = 0; q < 4; ++q) {
        const int j = q*256 + ks*4;
        float4 w4[4];
        if (blk < B_) {
          #pragma unroll
          for (int ri = 0; ri < 4; ++ri)
            w4[ri] = *(const float4*)(Wih1 + (ri*1024 + j0 + rg)*1024 + j);
        } else {
          #pragma unroll
          for (int ri = 0; ri < 4; ++ri)
            w4[ri] = *(const float4*)(xt + WLDS + (((ri*4 + rg)*4 + q) << 8) + ks*4);
        }
        #pragma unroll
        for (int bi = 0; bi < 8; ++bi) {
          const float4 xv = *(const float4*)(xt + (bgb+bi)*XST3 + j);
          #pragma unroll
          for (int ri = 0; ri < 4; ++ri)
            acc[ri][bi] += w4[ri].x*xv.x + w4[ri].y*xv.y + w4[ri].z*xv.z + w4[ri].w*xv.w;
        }
      }
      #pragma unroll
      for (int ri = 0; ri < 4; ++ri)
        #pragma unroll
        for (int bi = 0; bi < 8; ++bi) {
          float v = acc[ri][bi];
          REDUCE64(v);
          if (ks == 63) gv[(rg*4 + ri)*16 + (bgb+bi)] = v;
        }
      __syncthreads();
      if (tid < 64) {
        const int jl = tid >> 4, bb = tid & 15;
        const int j = j0 + jl;
        float pi, pf, pg, po;
        if (blk < B_) {
          const float4 g4 = ld1q_sys(g1pre + bb*256 + j*4);
          pi = g4.x; pf = g4.y; pg = g4.z; po = g4.w;
        } else {
          pi = gv1[(0*4 + jl)*16 + bb];
          pf = gv1[(1*4 + jl)*16 + bb];
          pg = gv1[(2*4 + jl)*16 + bb];
          po = gv1[(3*4 + jl)*16 + bb];
        }
        const float gi = gv[(jl*4+0)*16 + bb] + pi;
        const float gf = gv[(jl*4+1)*16 + bb] + pf;
        const float gg = gv[(jl*4+2)*16 + bb] + pg;
        const float go = gv[(jl*4+3)*16 + bb] + po;
        const float cn = fsigf(gf)*c1r + fsigf(gi)*ftanhf(gg);
        const float hn = fsigf(go)*ftanhf(cn);
        c1r = cn;
        st_sys(h1buf + cur*B_*DIM_ + bb*DIM_ + j, hn);
      }
    }
    gridbar(bar, tid, blk, ep); ++ep;
  }

  // ---- tail projection for t = T_-1 (step-299 h1/align live in slot 0)
  if (blk < B_) {
    const int b = blk;
    if (tid < 256) {
      float4 v = ld1q_sys(h1buf + b*DIM_ + tid*4);
      *(float4*)(projx + tid*4) = v;
    } else if (tid < 384) {
      const int j = tid - 256;
      float4 v = ld1q_sys(albuf + b*ENC_ + j*4);
      *(float4*)(projx + 1024 + j*4) = v;
    }
    __syncthreads();
    const int o = tid >> 2, part = tid & 3;
    if (o < 81) {
      const float* w = projW + o*1536;
      const int jb = part*384;
      float acc = 0.0f;
      for (int j = jb; j < jb + 384; j += 4) {
        const float4 wv = *(const float4*)(w + j);
        const float4 xv = *(const float4*)(projx + j);
        acc += wv.x*xv.x + wv.y*xv.y + wv.z*xv.z + wv.w*xv.w;
      }
      spf[o*4 + part] = acc;
    }
    __syncthreads();
    if (tid < 81) {
      const float v = projb[tid] + spf[tid*4] + spf[tid*4+1] + spf[tid*4+2] + spf[tid*4+3];
      if (tid < 80) out_mel[(b*NMEL_ + tid)*T_ + (T_-1)] = v;
      else          out_stop[b*T_ + (T_-1)] = v;
    }
  }
}

extern "C" void kernel_launch(void* const* d_in, const int* in_sizes, int n_in,
                              void* d_out, int out_size, void* d_ws, size_t ws_size,
                              hipStream_t stream) {
  const float* mels  = (const float*)d_in[0];
  const float* enc   = (const float*)d_in[1];
  const int*   tlen  = (const int*)d_in[2];
  const float* Wt    = (const float*)d_in[3];
  const float* Wq    = (const float*)d_in[4];
  const float* wsc   = (const float*)d_in[5];
  const float* conv1 = (const float*)d_in[6];
  const float* conv2 = (const float*)d_in[7];
  const float* pW1   = (const float*)d_in[8];
  const float* pb1   = (const float*)d_in[9];
  const float* pW2   = (const float*)d_in[10];
  const float* pb2   = (const float*)d_in[11];
  const float* Wih0  = (const float*)d_in[12];
  const float* Whh0  = (const float*)d_in[13];
  const float* bih0  = (const float*)d_in[14];
  const float* bhh0  = (const float*)d_in[15];
  const float* Wih1  = (const float*)d_in[16];
  const float* Whh1  = (const float*)d_in[17];
  const float* bih1  = (const float*)d_in[18];
  const float* bhh1  = (const float*)d_in[19];
  const float* h0    = (const float*)d_in[20];
  const float* c0    = (const float*)d_in[21];
  const float* projW = (const float*)d_in[22];
  const float* projb = (const float*)d_in[23];

  float* ws     = (float*)d_ws;
  float* melpre = ws;                  // 300*16*256   = 1228800
  float* lencb  = melpre + 1228800;    // 16*160*128   = 327680
  float* weff   = lencb + 327680;      // 128*32       = 4096
  float* h1buf  = weff + 4096;         // 2*16*1024    = 32768
  float* albuf  = h1buf + 32768;       // 2*16*512     = 16384
  float* h0st   = albuf + 16384;       // 16*1024      = 16384
  float* g0pre  = h0st + 16384;        // 16*256       = 4096
  float* g1pre  = g0pre + 4096;        // 16*256       = 4096
  u32*   bar    = (u32*)(g1pre + 4096);// 17408 words

  float* out_mel  = (float*)d_out;
  float* out_stop = out_mel + 384000;
  float* out_attn = out_stop + 4800;

  prenet_kernel<<<dim3(480), dim3(256), 0, stream>>>(mels, pW1, pb1, pW2, pb2, melpre);
  init_kernel<<<dim3(160), dim3(256), 0, stream>>>(h0, conv1, conv2, h1buf, h0st, weff, bar);
  lenc_kernel<<<dim3(640), dim3(256), 0, stream>>>(enc, Wt, lencb);

  void* args[] = {
    (void*)&melpre, (void*)&lencb, (void*)&weff, (void*)&h1buf, (void*)&albuf, (void*)&h0st,
    (void*)&g0pre, (void*)&g1pre, (void*)&bar,
    (void*)&enc, (void*)&tlen, (void*)&Wq, (void*)&wsc,
    (void*)&Wih0, (void*)&Whh0, (void*)&bih0, (void*)&bhh0,
    (void*)&Wih1, (void*)&Whh1, (void*)&bih1, (void*)&bhh1,
    (void*)&c0, (void*)&projW, (void*)&projb,
    (void*)&out_mel, (void*)&out_stop, (void*)&out_attn
  };
  hipLaunchCooperativeKernel((const void*)decoder_kernel, dim3(256), dim3(512),
                             args, (unsigned int)(XTOT*sizeof(float)), stream);
}